// Round 2
// baseline (1152.974 us; speedup 1.0000x reference)
//
#include <hip/hip_runtime.h>

// Palettized 3x3 VALID conv as implicit GEMM:
//   C[M=16*254*254, 64] = A[M, K=576] * B[K=576, 64],  K = (kh*3+kw)*64 + c
// Round-2: channel-split K loop. Only half the input channels (4 cblks = 32 ch)
// are resident in LDS at a time; the block stages half 0, computes the 9 even
// kc chunks, re-stages half 1 into the same buffer, computes the 9 odd chunks.
// LDS/block halves 50688 -> 25344 B => 6 blocks/CU (was 3), 24/32 waves.
// Latency hiding comes from inter-block overlap, not registers (round-1's
// reg-pipelined variant spilled: WRITE_SIZE 282->530 MB).

typedef __bf16 bf16x8 __attribute__((ext_vector_type(8)));
typedef float f32x4 __attribute__((ext_vector_type(4)));

union Frag {
    uint4 q;
    bf16x8 v;
};

// ---- B dequant/swizzle: Bws[s]  s = (kc*4 + nt)*64 + lane, 16B per slot.
// lane holds B[k = kc*32 + (lane>>4)*8 + j][o = nt*16 + (lane&15)], j=0..7
// with k = (kh*3+kw)*64 + c  ->  kc: r = kc>>1 fixed, c = (kc&1)*32 + (lane>>4)*8 + j.
__global__ __launch_bounds__(256) void dequant_B(
        const float* __restrict__ lut, const int* __restrict__ widx,
        uint4* __restrict__ Bws) {
    int s = blockIdx.x * 256 + threadIdx.x;   // 0..4607
    int l = s & 63;
    int nt = (s >> 6) & 3;
    int kc = s >> 8;
    if (kc >= 18) return;
    int r = kc >> 1;
    int kh = r / 3, kw = r - kh * 3;
    int o = nt * 16 + (l & 15);
    int c0 = (kc & 1) * 32 + (l >> 4) * 8;
    Frag f;
#pragma unroll
    for (int j = 0; j < 8; ++j) {
        int c = c0 + j;
        int idx = widx[((o * 64 + c) * 3 + kh) * 3 + kw];
        f.v[j] = (__bf16)lut[idx];
    }
    Bws[s] = f.q;
}

// LDS layout: ldsA[cb][pix] as 16B granules; pix = row*66 + col (row 0..5, col 0..65)
// cb = local channel block 0..3 (channels (half*4+cb)*8 .. +7 of pixel (row,col)).
#define LDS_PIX 396

__global__ __launch_bounds__(256, 6) void conv_mfma(
        const float* __restrict__ x, const float* __restrict__ bias,
        const uint4* __restrict__ Bws, float* __restrict__ out) {
    __shared__ uint4 ldsA[4 * LDS_PIX];   // 25344 B -> 6 blocks/CU

    int bx = blockIdx.x;
    int ow0 = (bx & 3) * 64;          // 0,64,128,192
    int oh0 = ((bx >> 2) & 63) * 4;   // 0..252
    int n = bx >> 8;                  // 0..15
    int t = threadIdx.x;

    const float* xn = x + (size_t)n * (64 * 256 * 256);

    int w = t >> 6;
    int l = t & 63;
    int l15 = l & 15, l4 = l >> 4;

    // staging-role constants
    int st_col = t & 63;
    int st_cb  = t >> 6;              // 0..3
    // tail: cols 64,65 (4 cb x 6 row x 2 col = 48 granules, t<48)
    int tl_cb  = t & 3;
    int tl_rc  = t >> 2;              // 0..11 for t<48
    int tl_rr  = tl_rc >> 1;
    int tl_col = 64 + (tl_rc & 1);
    int tl_xc  = ow0 + tl_col; if (tl_xc > 255) tl_xc = 255;

    f32x4 acc[4][4] = {};

    for (int h = 0; h < 2; ++h) {
        // ---- stage x[n, h*32:(h+1)*32, oh0:oh0+6, ow0:ow0+66] -> LDS (fp32->bf16)
        {
            const float* sb = xn + (h * 4 + st_cb) * (8 * 65536) + ow0 + st_col;
#pragma unroll
            for (int rr = 0; rr < 6; ++rr) {
                int y = oh0 + rr; if (y > 255) y = 255;
                const float* src = sb + y * 256;
                Frag f;
#pragma unroll
                for (int j = 0; j < 8; ++j)
                    f.v[j] = (__bf16)src[j * 65536];
                ldsA[st_cb * LDS_PIX + rr * 66 + st_col] = f.q;
            }
            if (t < 48) {
                int y = oh0 + tl_rr; if (y > 255) y = 255;
                const float* src = xn + (h * 4 + tl_cb) * (8 * 65536) + y * 256 + tl_xc;
                Frag f;
#pragma unroll
                for (int j = 0; j < 8; ++j)
                    f.v[j] = (__bf16)src[j * 65536];
                ldsA[tl_cb * LDS_PIX + tl_rr * 66 + tl_col] = f.q;
            }
        }
        __syncthreads();

        // ---- 9 kc chunks of parity h: kc = 2*i + h, r = kc>>1 = i
#pragma unroll
        for (int i = 0; i < 9; ++i) {
            int kh = i / 3, kw = i - kh * 3;     // block-uniform, compile-time
            int kc = 2 * i + h;
            int pix = (w + kh) * 66 + l15 + kw;

            Frag b[4];
#pragma unroll
            for (int nt = 0; nt < 4; ++nt)
                b[nt].q = Bws[(kc * 4 + nt) * 64 + l];

            Frag a[4];
#pragma unroll
            for (int mt = 0; mt < 4; ++mt)
                a[mt].q = ldsA[l4 * LDS_PIX + pix + mt * 16];

#pragma unroll
            for (int mt = 0; mt < 4; ++mt)
#pragma unroll
                for (int nt = 0; nt < 4; ++nt)
                    acc[mt][nt] = __builtin_amdgcn_mfma_f32_16x16x32_bf16(
                        a[mt].v, b[nt].v, acc[mt][nt], 0, 0, 0);
        }
        if (h == 0) __syncthreads();   // protect LDS before re-stage
    }

    // ---- epilogue: C/D layout col(o)=lane&15, row(ow_l)=(lane>>4)*4+reg
    int oh = oh0 + w;
    if (oh < 254) {
#pragma unroll
        for (int nt = 0; nt < 4; ++nt) {
            int o = nt * 16 + l15;
            float bv = bias[o];
            float* obase = out + (((size_t)n * 64 + o) * 254 + oh) * 254 + ow0;
#pragma unroll
            for (int mt = 0; mt < 4; ++mt) {
#pragma unroll
                for (int rg = 0; rg < 4; ++rg) {
                    int owl = mt * 16 + l4 * 4 + rg;
                    if (ow0 + owl < 254)
                        obase[owl] = acc[mt][nt][rg] + bv;
                }
            }
        }
    }
}

extern "C" void kernel_launch(void* const* d_in, const int* in_sizes, int n_in,
                              void* d_out, int out_size, void* d_ws, size_t ws_size,
                              hipStream_t stream) {
    const float* x    = (const float*)d_in[0];
    const float* lut  = (const float*)d_in[1];
    const int*   widx = (const int*)d_in[2];
    const float* bias = (const float*)d_in[3];
    float* out = (float*)d_out;
    uint4* Bws = (uint4*)d_ws;   // needs 73728 B

    dequant_B<<<18, 256, 0, stream>>>(lut, widx, Bws);
    conv_mfma<<<4096, 256, 0, stream>>>(x, bias, (const uint4*)Bws, out);
}

// Round 3
// 564.046 us; speedup vs baseline: 2.0441x; 2.0441x over previous
//
#include <hip/hip_runtime.h>

// Palettized 3x3 VALID conv as implicit GEMM:
//   C[M=16*254*254, 64] = A[M, K=576] * B[K=576, 64],  K = (kh*3+kw)*64 + c
// Round-3: occupancy via SMALLER PER-WAVE TILE, not register caps.
//   Block tile = 2 oh x 64 ow x 64 O; wave = 1 oh row x 32 ow x 64 O
//   -> acc[2][4] = 32 VGPRs (round-0's acc[4][4]=64 was the spill trigger).
// Channel-split K loop kept (stage 32ch -> 9 even kc -> restage -> 9 odd kc):
//   LDS = 4 cblk x (4 rows x 66 cols, pitch 266) x 16B = 17024 B.
// Expected ~6-7 blocks/CU (24-28 waves) vs round-0's 3 (12 waves).

typedef __bf16 bf16x8 __attribute__((ext_vector_type(8)));
typedef float f32x4 __attribute__((ext_vector_type(4)));

union Frag {
    uint4 q;
    bf16x8 v;
};

// ---- B dequant/swizzle: Bws[s]  s = (kc*4 + nt)*64 + lane, 16B per slot.
// lane holds B[k = kc*32 + (lane>>4)*8 + j][o = nt*16 + (lane&15)], j=0..7
// with k = (kh*3+kw)*64 + c  ->  kc: r = kc>>1 fixed, c = (kc&1)*32 + (lane>>4)*8 + j.
__global__ __launch_bounds__(256) void dequant_B(
        const float* __restrict__ lut, const int* __restrict__ widx,
        uint4* __restrict__ Bws) {
    int s = blockIdx.x * 256 + threadIdx.x;   // 0..4607
    int l = s & 63;
    int nt = (s >> 6) & 3;
    int kc = s >> 8;
    if (kc >= 18) return;
    int r = kc >> 1;
    int kh = r / 3, kw = r - kh * 3;
    int o = nt * 16 + (l & 15);
    int c0 = (kc & 1) * 32 + (l >> 4) * 8;
    Frag f;
#pragma unroll
    for (int j = 0; j < 8; ++j) {
        int c = c0 + j;
        int idx = widx[((o * 64 + c) * 3 + kh) * 3 + kw];
        f.v[j] = (__bf16)lut[idx];
    }
    Bws[s] = f.q;
}

// LDS layout: ldsA[cb][pix] as 16B granules; pix = row*66 + col (row 0..3, col 0..65)
// cb pitch padded to 266 granules so the 4 l4-groups land at banks {0,8,16,24}.
#define LDS_PIX 266

__global__ __launch_bounds__(256, 4) void conv_mfma(
        const float* __restrict__ x, const float* __restrict__ bias,
        const uint4* __restrict__ Bws, float* __restrict__ out) {
    __shared__ uint4 ldsA[4 * LDS_PIX];   // 17024 B

    int bx = blockIdx.x;
    int ow0 = (bx & 3) * 64;            // 0,64,128,192
    int oh0 = ((bx >> 2) & 127) * 2;    // 0..254 (oh0=254 blocks masked out)
    int n = bx >> 9;                    // 0..15
    int t = threadIdx.x;

    const float* xn = x + (size_t)n * (64 * 256 * 256);

    int w = t >> 6;                     // wave 0..3
    int l = t & 63;
    int l15 = l & 15, l4 = l >> 4;
    int ohl = w >> 1;                   // wave's oh row within tile (0..1)
    int owb = (w & 1) * 32;             // wave's ow base (0 or 32)

    // staging roles: main = (cb = t>>6, col = t&63, rows 0..3)
    int st_col = t & 63;
    int st_cb  = t >> 6;
    // tail cols 64,65: 4 cb x 4 rows x 2 cols = 32 granules (t<32)
    int tl_cb  = t & 3;
    int tl_rc  = t >> 2;                // 0..7 for t<32
    int tl_rr  = tl_rc >> 1;            // 0..3
    int tl_col = 64 + (tl_rc & 1);
    int tl_xc  = ow0 + tl_col; if (tl_xc > 255) tl_xc = 255;

    f32x4 acc[2][4] = {};

    for (int h = 0; h < 2; ++h) {
        // ---- stage x[n, h*32:(h+1)*32, oh0:oh0+4, ow0:ow0+66] -> LDS (fp32->bf16)
        {
            const float* sb = xn + (h * 4 + st_cb) * (8 * 65536) + ow0 + st_col;
#pragma unroll
            for (int rr = 0; rr < 4; ++rr) {
                int y = oh0 + rr; if (y > 255) y = 255;
                const float* src = sb + y * 256;
                Frag f;
#pragma unroll
                for (int j = 0; j < 8; ++j)
                    f.v[j] = (__bf16)src[j * 65536];
                ldsA[st_cb * LDS_PIX + rr * 66 + st_col] = f.q;
            }
            if (t < 32) {
                int y = oh0 + tl_rr; if (y > 255) y = 255;
                const float* src = xn + (h * 4 + tl_cb) * (8 * 65536) + y * 256 + tl_xc;
                Frag f;
#pragma unroll
                for (int j = 0; j < 8; ++j)
                    f.v[j] = (__bf16)src[j * 65536];
                ldsA[tl_cb * LDS_PIX + tl_rr * 66 + tl_col] = f.q;
            }
        }
        __syncthreads();

        // ---- 9 kc chunks of parity h: kc = 2*i + h, r = kc>>1 = i
#pragma unroll
        for (int i = 0; i < 9; ++i) {
            int kh = i / 3, kw = i - kh * 3;     // block-uniform, compile-time
            int kc = 2 * i + h;
            int pix = (ohl + kh) * 66 + owb + l15 + kw;

            Frag b[4];
#pragma unroll
            for (int nt = 0; nt < 4; ++nt)
                b[nt].q = Bws[(kc * 4 + nt) * 64 + l];

            Frag a[2];
#pragma unroll
            for (int mt = 0; mt < 2; ++mt)
                a[mt].q = ldsA[l4 * LDS_PIX + pix + mt * 16];

#pragma unroll
            for (int mt = 0; mt < 2; ++mt)
#pragma unroll
                for (int nt = 0; nt < 4; ++nt)
                    acc[mt][nt] = __builtin_amdgcn_mfma_f32_16x16x32_bf16(
                        a[mt].v, b[nt].v, acc[mt][nt], 0, 0, 0);
        }
        if (h == 0) __syncthreads();   // protect LDS before re-stage
    }

    // ---- epilogue: C/D layout col(o)=lane&15, row(ow_l)=(lane>>4)*4+reg
    int oh = oh0 + ohl;
    if (oh < 254) {
#pragma unroll
        for (int nt = 0; nt < 4; ++nt) {
            int o = nt * 16 + l15;
            float bv = bias[o];
            float* obase = out + (((size_t)n * 64 + o) * 254 + oh) * 254 + ow0;
#pragma unroll
            for (int mt = 0; mt < 2; ++mt) {
#pragma unroll
                for (int rg = 0; rg < 4; ++rg) {
                    int owl = owb + mt * 16 + l4 * 4 + rg;
                    if (ow0 + owl < 254)
                        obase[owl] = acc[mt][nt][rg] + bv;
                }
            }
        }
    }
}

extern "C" void kernel_launch(void* const* d_in, const int* in_sizes, int n_in,
                              void* d_out, int out_size, void* d_ws, size_t ws_size,
                              hipStream_t stream) {
    const float* x    = (const float*)d_in[0];
    const float* lut  = (const float*)d_in[1];
    const int*   widx = (const int*)d_in[2];
    const float* bias = (const float*)d_in[3];
    float* out = (float*)d_out;
    uint4* Bws = (uint4*)d_ws;   // needs 73728 B

    dequant_B<<<18, 256, 0, stream>>>(lut, widx, Bws);
    conv_mfma<<<8192, 256, 0, stream>>>(x, bias, (const uint4*)Bws, out);
}

// Round 4
// 546.571 us; speedup vs baseline: 2.1095x; 1.0320x over previous
//
#include <hip/hip_runtime.h>

// Palettized 3x3 VALID conv as implicit GEMM:
//   C[M=16*254*254, 64] = A[M, K=576] * B[K=576, 64],  K = (kh*3+kw)*64 + c
// Round-4: R0's proven compute tile (4 oh x 64 ow x 64 O, acc[4][4]) +
// channel-split K loop (stage 32ch -> 9 even kc -> restage -> 9 odd kc)
// so LDS halves to 25344 B => 6 blocks/CU by LDS. Crucially, launch_bounds
// stays (256,4): round-2 proved (256,6)'s 85-VGPR cap spills the 64-VGPR
// accumulator to scratch (VGPR=40, WRITE_SIZE 283->2050 MB). Natural VGPR
// (~72-80) allows 6 blocks/CU anyway (6 waves/SIMD x 80 = 480 <= 512).

typedef __bf16 bf16x8 __attribute__((ext_vector_type(8)));
typedef float f32x4 __attribute__((ext_vector_type(4)));

union Frag {
    uint4 q;
    bf16x8 v;
};

// ---- B dequant/swizzle: Bws[s]  s = (kc*4 + nt)*64 + lane, 16B per slot.
// lane holds B[k = kc*32 + (lane>>4)*8 + j][o = nt*16 + (lane&15)], j=0..7
// with k = (kh*3+kw)*64 + c  ->  kc: r = kc>>1 fixed, c = (kc&1)*32 + (lane>>4)*8 + j.
__global__ __launch_bounds__(256) void dequant_B(
        const float* __restrict__ lut, const int* __restrict__ widx,
        uint4* __restrict__ Bws) {
    int s = blockIdx.x * 256 + threadIdx.x;   // 0..4607
    int l = s & 63;
    int nt = (s >> 6) & 3;
    int kc = s >> 8;
    if (kc >= 18) return;
    int r = kc >> 1;
    int kh = r / 3, kw = r - kh * 3;
    int o = nt * 16 + (l & 15);
    int c0 = (kc & 1) * 32 + (l >> 4) * 8;
    Frag f;
#pragma unroll
    for (int j = 0; j < 8; ++j) {
        int c = c0 + j;
        int idx = widx[((o * 64 + c) * 3 + kh) * 3 + kw];
        f.v[j] = (__bf16)lut[idx];
    }
    Bws[s] = f.q;
}

// LDS layout: ldsA[cb][pix] as 16B granules; pix = row*66 + col (row 0..5, col 0..65)
// cb = local channel block 0..3 (channels (half*4+cb)*8 .. +7 of pixel (row,col)).
#define LDS_PIX 396

__global__ __launch_bounds__(256, 4) void conv_mfma(
        const float* __restrict__ x, const float* __restrict__ bias,
        const uint4* __restrict__ Bws, float* __restrict__ out) {
    __shared__ uint4 ldsA[4 * LDS_PIX];   // 25344 B -> 6 blocks/CU by LDS

    int bx = blockIdx.x;
    int ow0 = (bx & 3) * 64;          // 0,64,128,192
    int oh0 = ((bx >> 2) & 63) * 4;   // 0..252
    int n = bx >> 8;                  // 0..15
    int t = threadIdx.x;

    const float* xn = x + (size_t)n * (64 * 256 * 256);

    int w = t >> 6;
    int l = t & 63;
    int l15 = l & 15, l4 = l >> 4;

    // staging-role constants
    int st_col = t & 63;
    int st_cb  = t >> 6;              // 0..3
    // tail: cols 64,65 (4 cb x 6 row x 2 col = 48 granules, t<48)
    int tl_cb  = t & 3;
    int tl_rc  = t >> 2;              // 0..11 for t<48
    int tl_rr  = tl_rc >> 1;
    int tl_col = 64 + (tl_rc & 1);
    int tl_xc  = ow0 + tl_col; if (tl_xc > 255) tl_xc = 255;

    f32x4 acc[4][4] = {};

    for (int h = 0; h < 2; ++h) {
        // ---- stage x[n, h*32:(h+1)*32, oh0:oh0+6, ow0:ow0+66] -> LDS (fp32->bf16)
        {
            const float* sb = xn + (h * 4 + st_cb) * (8 * 65536) + ow0 + st_col;
#pragma unroll
            for (int rr = 0; rr < 6; ++rr) {
                int y = oh0 + rr; if (y > 255) y = 255;
                const float* src = sb + y * 256;
                Frag f;
#pragma unroll
                for (int j = 0; j < 8; ++j)
                    f.v[j] = (__bf16)src[j * 65536];
                ldsA[st_cb * LDS_PIX + rr * 66 + st_col] = f.q;
            }
            if (t < 48) {
                int y = oh0 + tl_rr; if (y > 255) y = 255;
                const float* src = xn + (h * 4 + tl_cb) * (8 * 65536) + y * 256 + tl_xc;
                Frag f;
#pragma unroll
                for (int j = 0; j < 8; ++j)
                    f.v[j] = (__bf16)src[j * 65536];
                ldsA[tl_cb * LDS_PIX + tl_rr * 66 + tl_col] = f.q;
            }
        }
        __syncthreads();

        // ---- 9 kc chunks of parity h: kc = 2*i + h, r = kc>>1 = i
#pragma unroll
        for (int i = 0; i < 9; ++i) {
            int kh = i / 3, kw = i - kh * 3;     // block-uniform, compile-time
            int kc = 2 * i + h;
            int pix = (w + kh) * 66 + l15 + kw;

            Frag b[4];
#pragma unroll
            for (int nt = 0; nt < 4; ++nt)
                b[nt].q = Bws[(kc * 4 + nt) * 64 + l];

            Frag a[4];
#pragma unroll
            for (int mt = 0; mt < 4; ++mt)
                a[mt].q = ldsA[l4 * LDS_PIX + pix + mt * 16];

#pragma unroll
            for (int mt = 0; mt < 4; ++mt)
#pragma unroll
                for (int nt = 0; nt < 4; ++nt)
                    acc[mt][nt] = __builtin_amdgcn_mfma_f32_16x16x32_bf16(
                        a[mt].v, b[nt].v, acc[mt][nt], 0, 0, 0);
        }
        if (h == 0) __syncthreads();   // protect LDS before re-stage
    }

    // ---- epilogue: C/D layout col(o)=lane&15, row(ow_l)=(lane>>4)*4+reg
    int oh = oh0 + w;
    if (oh < 254) {
#pragma unroll
        for (int nt = 0; nt < 4; ++nt) {
            int o = nt * 16 + l15;
            float bv = bias[o];
            float* obase = out + (((size_t)n * 64 + o) * 254 + oh) * 254 + ow0;
#pragma unroll
            for (int mt = 0; mt < 4; ++mt) {
#pragma unroll
                for (int rg = 0; rg < 4; ++rg) {
                    int owl = mt * 16 + l4 * 4 + rg;
                    if (ow0 + owl < 254)
                        obase[owl] = acc[mt][nt][rg] + bv;
                }
            }
        }
    }
}

extern "C" void kernel_launch(void* const* d_in, const int* in_sizes, int n_in,
                              void* d_out, int out_size, void* d_ws, size_t ws_size,
                              hipStream_t stream) {
    const float* x    = (const float*)d_in[0];
    const float* lut  = (const float*)d_in[1];
    const int*   widx = (const int*)d_in[2];
    const float* bias = (const float*)d_in[3];
    float* out = (float*)d_out;
    uint4* Bws = (uint4*)d_ws;   // needs 73728 B

    dequant_B<<<18, 256, 0, stream>>>(lut, widx, Bws);
    conv_mfma<<<4096, 256, 0, stream>>>(x, bias, (const uint4*)Bws, out);
}

// Round 5
// 515.131 us; speedup vs baseline: 2.2382x; 1.0610x over previous
//
#include <hip/hip_runtime.h>

// Palettized 3x3 VALID conv as implicit GEMM:
//   C[M=16*254*254, 64] = A[M, K=576] * B[K=576, 64],  K = (kh*3+kw)*64 + c
// Round-5: R0 structure (4 oh x 64 ow x 64 O tile, single stage, 18-kc loop,
// 3 blocks/CU) with MLP-fixed staging. Old stage = scalar dword loads, 8 in
// flight (2 KB/wave) -> Little's law caps BW at ~2.5-2.8 TB/s (matches
// R0/R3/R4 regardless of occupancy; R2's spill traffic proved 3.78 TB/s is
// reachable). New stage: lane = (colg 0..15 x chpair 0..3); per cblk-row each
// lane does 2x global_load_dwordx4 (4 cols x 2 channels), batched 6 rows
// -> 12 KB in flight per wave. LDS byte layout unchanged (u32 = packed bf16
// channel pair scattered via ds_write_b32); read/compute/epilogue identical.

typedef __bf16 bf16x8 __attribute__((ext_vector_type(8)));
typedef float f32x4 __attribute__((ext_vector_type(4)));

union Frag {
    uint4 q;
    bf16x8 v;
};

// ---- B dequant/swizzle: Bws[s]  s = (kc*4 + nt)*64 + lane, 16B per slot.
// lane holds B[k = kc*32 + (lane>>4)*8 + j][o = nt*16 + (lane&15)], j=0..7
// with k = (kh*3+kw)*64 + c  ->  kc: r = kc>>1 fixed, c = (kc&1)*32 + (lane>>4)*8 + j.
__global__ __launch_bounds__(256) void dequant_B(
        const float* __restrict__ lut, const int* __restrict__ widx,
        uint4* __restrict__ Bws) {
    int s = blockIdx.x * 256 + threadIdx.x;   // 0..4607
    int l = s & 63;
    int nt = (s >> 6) & 3;
    int kc = s >> 8;
    if (kc >= 18) return;
    int r = kc >> 1;
    int kh = r / 3, kw = r - kh * 3;
    int o = nt * 16 + (l & 15);
    int c0 = (kc & 1) * 32 + (l >> 4) * 8;
    Frag f;
#pragma unroll
    for (int j = 0; j < 8; ++j) {
        int c = c0 + j;
        int idx = widx[((o * 64 + c) * 3 + kh) * 3 + kw];
        f.v[j] = (__bf16)lut[idx];
    }
    Bws[s] = f.q;
}

// LDS layout: ldsA[cblk][pix] as 16B granules; pix = row*66 + col (row 0..5, col 0..65)
// granule = 8 bf16 = channels cblk*8 .. cblk*8+7 of pixel (row,col);
// u32 word k of a granule = packed (ch 2k, ch 2k+1).
#define LDS_PIX 396

__global__ __launch_bounds__(256, 3) void conv_mfma(
        const float* __restrict__ x, const float* __restrict__ bias,
        const uint4* __restrict__ Bws, float* __restrict__ out) {
    __shared__ uint4 ldsA[8 * LDS_PIX];   // 50688 B
    unsigned* lds32 = (unsigned*)ldsA;

    int bx = blockIdx.x;
    int ow0 = (bx & 3) * 64;          // 0,64,128,192
    int oh0 = ((bx >> 2) & 63) * 4;   // 0..252
    int n = bx >> 8;                  // 0..15
    int t = threadIdx.x;

    const float* xn = x + (size_t)n * (64 * 256 * 256);

    int w = t >> 6;
    int l = t & 63;
    int l15 = l & 15, l4 = l >> 4;

    // ---- stage x[n, 0:64, oh0:oh0+6, ow0:ow0+66] -> LDS (fp32 -> bf16)
    // main cols 0..63: wave w covers cblk {w, w+4}; lane = (colg=l&15, chp=l>>4).
    // Per cblk-row: lane loads float4 (cols colg*4..+3) of channels chp*2, chp*2+1,
    // writes 4 packed u32 into LDS. 6 rows batched -> 12 dwordx4 in flight/wave.
    {
        int colg = l15;
        int chp  = l4;                 // 0..3
        const float* xw = xn + ow0 + colg * 4;
#pragma unroll
        for (int cc = 0; cc < 2; ++cc) {
            int cb = w + cc * 4;       // wave-uniform cblk
            const float* cbase = xw + (cb * 8 + chp * 2) * 65536;
            f32x4 f0[6], f1[6];
#pragma unroll
            for (int rr = 0; rr < 6; ++rr) {
                int y = oh0 + rr; if (y > 255) y = 255;
                const float* p = cbase + y * 256;
                f0[rr] = *(const f32x4*)(p);
                f1[rr] = *(const f32x4*)(p + 65536);
            }
#pragma unroll
            for (int rr = 0; rr < 6; ++rr) {
                int gbase = cb * LDS_PIX + rr * 66 + colg * 4;
#pragma unroll
                for (int i = 0; i < 4; ++i) {
                    union { __bf16 h[2]; unsigned u; } bp;
                    bp.h[0] = (__bf16)f0[rr][i];
                    bp.h[1] = (__bf16)f1[rr][i];
                    lds32[(gbase + i) * 4 + chp] = bp.u;
                }
            }
        }
        // tail: cols 64,65 (6 rows x 2 cols x 8 cblks = 96 granules), scalar path
        if (t < 96) {
            int cblk = t & 7;
            int rc = t >> 3;            // 0..11
            int rr = rc >> 1;
            int col2 = 64 + (rc & 1);
            int y = oh0 + rr; if (y > 255) y = 255;
            int xc = ow0 + col2; if (xc > 255) xc = 255;
            const float* src = xn + cblk * 8 * 65536 + y * 256 + xc;
            Frag f;
#pragma unroll
            for (int j = 0; j < 8; ++j)
                f.v[j] = (__bf16)src[j * 65536];
            ldsA[cblk * LDS_PIX + rr * 66 + col2] = f.q;
        }
    }
    __syncthreads();

    // ---- main GEMM: wave w handles oh row (oh0+w) x 64 ow x 64 O
    f32x4 acc[4][4] = {};

    for (int kc = 0; kc < 18; ++kc) {
        int r = kc >> 1;
        int kh = r / 3, kw = r - kh * 3;       // block-uniform
        int cblk = (kc & 1) * 4 + l4;
        int pix = (w + kh) * 66 + l15 + kw;

        Frag b[4];
#pragma unroll
        for (int nt = 0; nt < 4; ++nt)
            b[nt].q = Bws[(kc * 4 + nt) * 64 + l];

        Frag a[4];
#pragma unroll
        for (int mt = 0; mt < 4; ++mt)
            a[mt].q = ldsA[cblk * LDS_PIX + pix + mt * 16];

#pragma unroll
        for (int mt = 0; mt < 4; ++mt)
#pragma unroll
            for (int nt = 0; nt < 4; ++nt)
                acc[mt][nt] = __builtin_amdgcn_mfma_f32_16x16x32_bf16(
                    a[mt].v, b[nt].v, acc[mt][nt], 0, 0, 0);
    }

    // ---- epilogue: C/D layout col(o)=lane&15, row(ow_l)=(lane>>4)*4+reg
    int oh = oh0 + w;
    if (oh < 254) {
#pragma unroll
        for (int nt = 0; nt < 4; ++nt) {
            int o = nt * 16 + l15;
            float bv = bias[o];
            float* obase = out + (((size_t)n * 64 + o) * 254 + oh) * 254 + ow0;
#pragma unroll
            for (int mt = 0; mt < 4; ++mt) {
#pragma unroll
                for (int rg = 0; rg < 4; ++rg) {
                    int owl = mt * 16 + l4 * 4 + rg;
                    if (ow0 + owl < 254)
                        obase[owl] = acc[mt][nt][rg] + bv;
                }
            }
        }
    }
}

extern "C" void kernel_launch(void* const* d_in, const int* in_sizes, int n_in,
                              void* d_out, int out_size, void* d_ws, size_t ws_size,
                              hipStream_t stream) {
    const float* x    = (const float*)d_in[0];
    const float* lut  = (const float*)d_in[1];
    const int*   widx = (const int*)d_in[2];
    const float* bias = (const float*)d_in[3];
    float* out = (float*)d_out;
    uint4* Bws = (uint4*)d_ws;   // needs 73728 B

    dequant_B<<<18, 256, 0, stream>>>(lut, widx, Bws);
    conv_mfma<<<4096, 256, 0, stream>>>(x, bias, (const uint4*)Bws, out);
}